// Round 1
// baseline (627.527 us; speedup 1.0000x reference)
//
#include <hip/hip_runtime.h>

// HiddenMarkovGFormulaV2: N independent sequential filters over T=64 steps.
// Memory-bound streaming problem (~518 MB ideal traffic -> ~82 us floor).
//
// v2 changes vs baseline (216 us kernel, 28% occupancy, LDS-limited):
//  * Y packed into sign bit of C (exact: Y in {0,1}, C >= 0,
//    bits(1.0f)<<8 == 0x80000000) -> 2 LDS arrays instead of 3.
//  * CT 16 -> 8: LDS 50.2 KB -> 16.7 KB per block -> 8 blocks/CU
//    (wave-limited) instead of 3; __launch_bounds__(256,8) caps VGPR at 64.
//  * Inner step strength-reduced: y*log(p)+(1-y)*log(1-p) == log(sel) for
//    binary y -> ONE native v_log_f32 (accumulate in log2, scale by ln2 once);
//    native v_exp_f32 sigmoid; both divides -> single v_rcp_f32 each
//    (1/(1/v+h) == v/(1+v*h)); G-dependent coefficients hoisted.

#define TT 64          // timesteps (fixed by reference)
#define KK 3           // covariates (fixed by reference)
#define NB 256         // individuals per block == block size
#define CT 8           // timesteps per LDS tile
#define LDP (NB + 4)   // LDS leading-dim pad: 260 mod 32 == 4 -> 2-way (free)

__global__ void zero_ll_kernel(float* ll) { *ll = 0.0f; }

__global__ __launch_bounds__(NB, 8) void hmm_filter_kernel(
    const float* __restrict__ G,   // (N,1)
    const float* __restrict__ S,   // (N,T)
    const float* __restrict__ C,   // (N,T)
    const float* __restrict__ Y,   // (N,T)
    const float* __restrict__ L,   // (N,K)
    const float* __restrict__ p_psi,
    const float* __restrict__ p_gS,
    const float* __restrict__ p_gC,
    const float* __restrict__ p_gG,
    const float* __restrict__ p_gGS,
    const float* __restrict__ p_gGC,
    const float* __restrict__ p_gLw,  // (1,K)
    const float* __restrict__ p_lsZ,
    const float* __restrict__ p_b0,
    const float* __restrict__ p_bZ,
    const float* __restrict__ p_bS,
    const float* __restrict__ p_bG,
    const float* __restrict__ p_bGS,
    const float* __restrict__ p_bLw,  // (1,K)
    float* __restrict__ Zf,           // (N,T)
    float* __restrict__ Zv,           // (N,T)
    float* __restrict__ ll_out,       // scalar
    int N)
{
    __shared__ float sS [CT][LDP];    // in: S        out: Z_filtered
    __shared__ float sCY[CT][LDP];    // in: C|sign(Y) out: Z_variance
    __shared__ float wave_ll[NB / 64];

    const int tid = threadIdx.x;
    const int n0  = blockIdx.x * NB;
    const int n   = n0 + tid;
    const bool valid = (n < N);

    // --- uniform parameters (scalar-cached broadcast loads) ---
    const float psi  = p_psi[0];
    const float gS   = p_gS[0];
    const float gC   = p_gC[0];
    const float gG   = p_gG[0];
    const float gGS  = p_gGS[0];
    const float gGC  = p_gGC[0];
    const float b0   = p_b0[0];
    const float bZ   = p_bZ[0];
    const float bS   = p_bS[0];
    const float bG   = p_bG[0];
    const float bGS  = p_bGS[0];
    const float esz  = expf(p_lsZ[0]);
    const float sigma2 = esz * esz;
    const float psi2 = psi * psi;
    const float bZ2  = bZ * bZ;
    const float gw0 = p_gLw[0], gw1 = p_gLw[1], gw2 = p_gLw[2];
    const float bw0 = p_bLw[0], bw1 = p_bLw[1], bw2 = p_bLw[2];

    // --- per-n constants: fold G and L into per-thread coefficients ---
    float a_s = 0.0f, a_c = 0.0f, zbase = 0.0f, b_s = 0.0f, lbase = 0.0f;
    if (valid) {
        const float Gv = G[n];
        const float l0 = L[n * KK + 0];
        const float l1 = L[n * KK + 1];
        const float l2 = L[n * KK + 2];
        const float gL = l0 * gw0 + l1 * gw1 + l2 * gw2;
        const float bL = l0 * bw0 + l1 * bw1 + l2 * bw2;
        a_s   = gS + gGS * Gv;           // coeff of S_t in transition
        a_c   = gC + gGC * Gv;           // coeff of C_t in transition
        zbase = gG * Gv + gL;            // constant transition term
        b_s   = bS + bGS * Gv;           // coeff of S_t in logit
        lbase = b0 + bG * Gv + bL;       // constant logit term
    } else {
        lbase = b0;                      // keep math finite for dead lanes
    }

    float zm  = 0.0f;   // Z_mean
    float zv  = 1.0f;   // Z_var
    float ll2 = 0.0f;   // log-likelihood accumulated in log2 domain

    const float4* S4 = (const float4*)S;
    const float4* C4 = (const float4*)C;
    const float4* Y4 = (const float4*)Y;
    float4* Zf4 = (float4*)Zf;
    float4* Zv4 = (float4*)Zv;

    for (int t0 = 0; t0 < TT; t0 += CT) {
        // --- cooperative load: NB rows x CT floats, float4-granular ---
        // q indexes NB*CT/4 float4s; r = row (n-local), c = which float4.
        #pragma unroll
        for (int q = tid; q < NB * CT / 4; q += NB) {
            const int r  = q >> 1;        // CT/4 == 2 float4 per row
            const int c  = q & 1;
            const int nn = n0 + r;
            float4 vs, vc, vy;
            if (nn < N) {
                const int gidx = nn * (TT / 4) + (t0 >> 2) + c;
                vs = S4[gidx];
                vc = C4[gidx];
                vy = Y4[gidx];
            } else {
                vs = make_float4(0, 0, 0, 0);
                vc = vs; vy = vs;
            }
            const int tb = c * 4;
            sS[tb + 0][r] = vs.x; sS[tb + 1][r] = vs.y;
            sS[tb + 2][r] = vs.z; sS[tb + 3][r] = vs.w;
            // pack Y into sign of C: bits(1.0f)<<8 == 0x80000000, bits(0.0f)==0
            sCY[tb + 0][r] = __uint_as_float(__float_as_uint(vc.x) | (__float_as_uint(vy.x) << 8));
            sCY[tb + 1][r] = __uint_as_float(__float_as_uint(vc.y) | (__float_as_uint(vy.y) << 8));
            sCY[tb + 2][r] = __uint_as_float(__float_as_uint(vc.z) | (__float_as_uint(vy.z) << 8));
            sCY[tb + 3][r] = __uint_as_float(__float_as_uint(vc.w) | (__float_as_uint(vy.w) << 8));
        }
        __syncthreads();

        // --- sequential filter over this tile's CT steps ---
        // Each (t, tid) LDS slot is read then overwritten by exactly this
        // thread -> in-place output staging is race-free.
        #pragma unroll
        for (int t = 0; t < CT; ++t) {
            const float s    = sS[t][tid];
            const unsigned cyb = __float_as_uint(sCY[t][tid]);
            const float c    = __uint_as_float(cyb & 0x7fffffffu);
            const bool  yb   = (cyb >> 31) != 0u;

            const float zpred = fmaf(psi, zm, fmaf(a_s, s, fmaf(a_c, c, zbase)));
            const float zpvar = fmaf(psi2, zv, sigma2);

            float logit = fmaf(bZ, zpred, fmaf(b_s, s, lbase));
            logit = fminf(fmaxf(logit, -20.0f), 20.0f);
            // sigmoid: one v_exp_f32 + one v_rcp_f32
            const float p   = __builtin_amdgcn_rcpf(1.0f + __expf(-logit));
            const float omp = 1.0f - p;

            const float ymp = yb ? omp : -p;     // (y - p), y in {0,1}
            const float sel = yb ? p : omp;      // prob of observed outcome

            const float hess = fmaf(bZ2 * p, omp, 1e-6f);
            // 1/(1/zpvar + hess) == zpvar / (1 + zpvar*hess): one v_rcp_f32
            const float zpostvar  = zpvar * __builtin_amdgcn_rcpf(fmaf(zpvar, hess, 1.0f));
            const float zpostmean = fmaf(zpostvar * bZ, ymp, zpred);

            // y*log(p+e) + (1-y)*log(1-p+e) == log(sel+e) for binary y;
            // accumulate log2, scale by ln2 once after the loop.
            ll2 += __log2f(sel + 1e-10f);

            zm = zpostmean;
            zv = zpostvar;
            sS [t][tid] = zpostmean;   // stage Z_filtered
            sCY[t][tid] = zpostvar;    // stage Z_variance
        }
        __syncthreads();

        // --- cooperative store of staged outputs ---
        #pragma unroll
        for (int q = tid; q < NB * CT / 4; q += NB) {
            const int r  = q >> 1;
            const int c  = q & 1;
            const int nn = n0 + r;
            if (nn < N) {
                const int tb = c * 4;
                float4 vf, vv;
                vf.x = sS [tb + 0][r]; vf.y = sS [tb + 1][r];
                vf.z = sS [tb + 2][r]; vf.w = sS [tb + 3][r];
                vv.x = sCY[tb + 0][r]; vv.y = sCY[tb + 1][r];
                vv.z = sCY[tb + 2][r]; vv.w = sCY[tb + 3][r];
                const int gidx = nn * (TT / 4) + (t0 >> 2) + c;
                Zf4[gidx] = vf;
                Zv4[gidx] = vv;
            }
        }
        __syncthreads();  // protect LDS before next tile's load overwrites
    }

    // --- log-likelihood reduction: wave shuffle -> LDS -> one atomic/block ---
    float ll = valid ? ll2 * 0.69314718055994531f : 0.0f;
    #pragma unroll
    for (int off = 32; off > 0; off >>= 1) {
        ll += __shfl_down(ll, off, 64);
    }
    const int wid  = tid >> 6;
    const int lane = tid & 63;
    if (lane == 0) wave_ll[wid] = ll;
    __syncthreads();
    if (tid == 0) {
        float sacc = 0.0f;
        #pragma unroll
        for (int w = 0; w < NB / 64; ++w) sacc += wave_ll[w];
        atomicAdd(ll_out, sacc);
    }
}

extern "C" void kernel_launch(void* const* d_in, const int* in_sizes, int n_in,
                              void* d_out, int out_size, void* d_ws, size_t ws_size,
                              hipStream_t stream) {
    const int N = in_sizes[0];  // G is (N,1)

    const float* G   = (const float*)d_in[0];
    const float* S   = (const float*)d_in[1];
    const float* C   = (const float*)d_in[2];
    const float* Y   = (const float*)d_in[3];
    const float* L   = (const float*)d_in[4];
    const float* psi = (const float*)d_in[5];
    const float* gS  = (const float*)d_in[6];
    const float* gC  = (const float*)d_in[7];
    const float* gG  = (const float*)d_in[8];
    const float* gGS = (const float*)d_in[9];
    const float* gGC = (const float*)d_in[10];
    const float* gLw = (const float*)d_in[11];
    const float* lsZ = (const float*)d_in[12];
    const float* b0  = (const float*)d_in[13];
    const float* bZ  = (const float*)d_in[14];
    const float* bS  = (const float*)d_in[15];
    const float* bG  = (const float*)d_in[16];
    const float* bGS = (const float*)d_in[17];
    const float* bLw = (const float*)d_in[18];

    float* out = (float*)d_out;
    float* Zf = out;
    float* Zv = out + (size_t)N * TT;
    float* ll = out + (size_t)2 * N * TT;

    zero_ll_kernel<<<1, 1, 0, stream>>>(ll);

    const int blocks = (N + NB - 1) / NB;
    hmm_filter_kernel<<<blocks, NB, 0, stream>>>(
        G, S, C, Y, L, psi, gS, gC, gG, gGS, gGC, gLw, lsZ,
        b0, bZ, bS, bG, bGS, bLw, Zf, Zv, ll, N);
}

// Round 2
// 505.807 us; speedup vs baseline: 1.2406x; 1.2406x over previous
//
#include <hip/hip_runtime.h>

// HiddenMarkovGFormulaV2: N independent sequential filters over T=64 steps.
// Memory-bound streaming problem (~518 MB ideal traffic -> ~82 us floor).
//
// v3 changes vs v2 (309 us, FETCH 597 MB = 2x overfetch, latency-exposed):
//  * CT 8 -> 16: each row loads a full aligned 64 B per tile -> fetch
//    granularity clean, FETCH back to ~302 MB. Two LDS arrays (Y packed
//    into sign of C) keep LDS at 33.4 KB -> 4 blocks/CU.
//  * Register-prefetch software pipeline: next tile's 12 float4s are
//    issued right after the current tile's LDS staging, so HBM latency
//    overlaps the ~1000-cycle compute phase instead of stalling every
//    tile at s_waitcnt vmcnt(0). (v1/v2 were stuck at 2.4-2.65 TB/s
//    because every tile paid full latency and blocks phase-locked.)
//  * Inner step keeps v2's strength reduction: one v_exp_f32 sigmoid,
//    one v_log2_f32 for ll (binary y -> log(sel)), v_rcp_f32 for both
//    divides, G/L folded into per-thread coefficients.

#define TT 64          // timesteps (fixed by reference)
#define KK 3           // covariates (fixed by reference)
#define NB 256         // individuals per block == block size
#define CT 16          // timesteps per LDS tile (64 B per row per tile)
#define LDP (NB + 4)   // LDS leading-dim pad: 260 mod 32 == 4 -> 2-way (free)

__global__ void zero_ll_kernel(float* ll) { *ll = 0.0f; }

__global__ __launch_bounds__(NB, 4) void hmm_filter_kernel(
    const float* __restrict__ G,   // (N,1)
    const float* __restrict__ S,   // (N,T)
    const float* __restrict__ C,   // (N,T)
    const float* __restrict__ Y,   // (N,T)
    const float* __restrict__ L,   // (N,K)
    const float* __restrict__ p_psi,
    const float* __restrict__ p_gS,
    const float* __restrict__ p_gC,
    const float* __restrict__ p_gG,
    const float* __restrict__ p_gGS,
    const float* __restrict__ p_gGC,
    const float* __restrict__ p_gLw,  // (1,K)
    const float* __restrict__ p_lsZ,
    const float* __restrict__ p_b0,
    const float* __restrict__ p_bZ,
    const float* __restrict__ p_bS,
    const float* __restrict__ p_bG,
    const float* __restrict__ p_bGS,
    const float* __restrict__ p_bLw,  // (1,K)
    float* __restrict__ Zf,           // (N,T)
    float* __restrict__ Zv,           // (N,T)
    float* __restrict__ ll_out,       // scalar
    int N)
{
    __shared__ float sS [CT][LDP];    // in: S         out: Z_filtered
    __shared__ float sCY[CT][LDP];    // in: C|sign(Y) out: Z_variance
    __shared__ float wave_ll[NB / 64];

    const int tid = threadIdx.x;
    const int n0  = blockIdx.x * NB;
    const int n   = n0 + tid;
    const bool valid = (n < N);

    // --- uniform parameters (scalar-cached broadcast loads) ---
    const float psi  = p_psi[0];
    const float gS   = p_gS[0];
    const float gC   = p_gC[0];
    const float gG   = p_gG[0];
    const float gGS  = p_gGS[0];
    const float gGC  = p_gGC[0];
    const float b0   = p_b0[0];
    const float bZ   = p_bZ[0];
    const float bS   = p_bS[0];
    const float bG   = p_bG[0];
    const float bGS  = p_bGS[0];
    const float esz  = expf(p_lsZ[0]);
    const float sigma2 = esz * esz;
    const float psi2 = psi * psi;
    const float bZ2  = bZ * bZ;
    const float gw0 = p_gLw[0], gw1 = p_gLw[1], gw2 = p_gLw[2];
    const float bw0 = p_bLw[0], bw1 = p_bLw[1], bw2 = p_bLw[2];

    // --- per-n constants: fold G and L into per-thread coefficients ---
    float a_s = 0.0f, a_c = 0.0f, zbase = 0.0f, b_s = 0.0f, lbase = 0.0f;
    if (valid) {
        const float Gv = G[n];
        const float l0 = L[n * KK + 0];
        const float l1 = L[n * KK + 1];
        const float l2 = L[n * KK + 2];
        const float gL = l0 * gw0 + l1 * gw1 + l2 * gw2;
        const float bL = l0 * bw0 + l1 * bw1 + l2 * bw2;
        a_s   = gS + gGS * Gv;           // coeff of S_t in transition
        a_c   = gC + gGC * Gv;           // coeff of C_t in transition
        zbase = gG * Gv + gL;            // constant transition term
        b_s   = bS + bGS * Gv;           // coeff of S_t in logit
        lbase = b0 + bG * Gv + bL;       // constant logit term
    } else {
        lbase = b0;                      // keep math finite for dead lanes
    }

    float zm  = 0.0f;   // Z_mean
    float zv  = 1.0f;   // Z_var
    float ll2 = 0.0f;   // log-likelihood accumulated in log2 domain

    const float4* S4 = (const float4*)S;
    const float4* C4 = (const float4*)C;
    const float4* Y4 = (const float4*)Y;
    float4* Zf4 = (float4*)Zf;
    float4* Zv4 = (float4*)Zv;

    // Cooperative-load decomposition: q = tid + i*NB over NB*CT/4 = 1024
    // float4s; row r = q>>2, col c = q&3. For NB=256 this gives each
    // thread a FIXED float4-column cc = tid&3 and rows rbase + i*64.
    const int rbase = tid >> 2;          // 0..63
    const int cc    = tid & 3;           // which float4 within the row-tile
    const int tb    = cc * 4;            // first timestep of that float4

    float4 rs[4], rc[4], ry[4];          // prefetch registers (48 VGPRs)

    // --- prologue: prefetch tile 0 ---
    #pragma unroll
    for (int i = 0; i < 4; ++i) {
        const int nn = n0 + rbase + i * 64;
        if (nn < N) {
            const int gidx = nn * (TT / 4) + cc;
            rs[i] = S4[gidx]; rc[i] = C4[gidx]; ry[i] = Y4[gidx];
        } else {
            rs[i] = make_float4(0, 0, 0, 0);
            rc[i] = rs[i]; ry[i] = rs[i];
        }
    }

    for (int t0 = 0; t0 < TT; t0 += CT) {
        // --- stage prefetched regs -> LDS (transpose + Y sign-pack) ---
        // pack: bits(1.0f)<<8 == 0x80000000, bits(0.0f) == 0; C >= 0.
        #pragma unroll
        for (int i = 0; i < 4; ++i) {
            const int r = rbase + i * 64;
            sS[tb + 0][r] = rs[i].x; sS[tb + 1][r] = rs[i].y;
            sS[tb + 2][r] = rs[i].z; sS[tb + 3][r] = rs[i].w;
            sCY[tb + 0][r] = __uint_as_float(__float_as_uint(rc[i].x) | (__float_as_uint(ry[i].x) << 8));
            sCY[tb + 1][r] = __uint_as_float(__float_as_uint(rc[i].y) | (__float_as_uint(ry[i].y) << 8));
            sCY[tb + 2][r] = __uint_as_float(__float_as_uint(rc[i].z) | (__float_as_uint(ry[i].z) << 8));
            sCY[tb + 3][r] = __uint_as_float(__float_as_uint(rc[i].w) | (__float_as_uint(ry[i].w) << 8));
        }
        __syncthreads();

        // --- issue next tile's global loads (overlap with compute) ---
        if (t0 + CT < TT) {
            const int fo = ((t0 + CT) >> 2) + cc;
            #pragma unroll
            for (int i = 0; i < 4; ++i) {
                const int nn = n0 + rbase + i * 64;
                if (nn < N) {           // invalid rows keep their zeros
                    const int gidx = nn * (TT / 4) + fo;
                    rs[i] = S4[gidx]; rc[i] = C4[gidx]; ry[i] = Y4[gidx];
                }
            }
        }

        // --- sequential filter over this tile's CT steps ---
        // Each (t, tid) LDS slot is read then overwritten by exactly this
        // thread -> in-place output staging is race-free.
        #pragma unroll
        for (int t = 0; t < CT; ++t) {
            const float s      = sS[t][tid];
            const unsigned cyb = __float_as_uint(sCY[t][tid]);
            const float c      = __uint_as_float(cyb & 0x7fffffffu);
            const bool  yb     = (cyb >> 31) != 0u;

            const float zpred = fmaf(psi, zm, fmaf(a_s, s, fmaf(a_c, c, zbase)));
            const float zpvar = fmaf(psi2, zv, sigma2);

            float logit = fmaf(bZ, zpred, fmaf(b_s, s, lbase));
            logit = fminf(fmaxf(logit, -20.0f), 20.0f);
            // sigmoid: one v_exp_f32 + one v_rcp_f32
            const float p   = __builtin_amdgcn_rcpf(1.0f + __expf(-logit));
            const float omp = 1.0f - p;

            const float ymp = yb ? omp : -p;     // (y - p), y in {0,1}
            const float sel = yb ? p : omp;      // prob of observed outcome

            const float hess = fmaf(bZ2 * p, omp, 1e-6f);
            // 1/(1/zpvar + hess) == zpvar/(1 + zpvar*hess): one v_rcp_f32
            const float zpostvar  = zpvar * __builtin_amdgcn_rcpf(fmaf(zpvar, hess, 1.0f));
            const float zpostmean = fmaf(zpostvar * bZ, ymp, zpred);

            // y*log(p+e) + (1-y)*log(1-p+e) == log(sel+e) for binary y;
            // accumulate log2, scale by ln2 once after the loop.
            ll2 += __log2f(sel + 1e-10f);

            zm = zpostmean;
            zv = zpostvar;
            sS [t][tid] = zpostmean;   // stage Z_filtered
            sCY[t][tid] = zpostvar;    // stage Z_variance
        }
        __syncthreads();

        // --- cooperative store of staged outputs (full 64 B per row) ---
        #pragma unroll
        for (int i = 0; i < 4; ++i) {
            const int r  = rbase + i * 64;
            const int nn = n0 + r;
            if (nn < N) {
                float4 vf, vv;
                vf.x = sS [tb + 0][r]; vf.y = sS [tb + 1][r];
                vf.z = sS [tb + 2][r]; vf.w = sS [tb + 3][r];
                vv.x = sCY[tb + 0][r]; vv.y = sCY[tb + 1][r];
                vv.z = sCY[tb + 2][r]; vv.w = sCY[tb + 3][r];
                const int gidx = nn * (TT / 4) + (t0 >> 2) + cc;
                Zf4[gidx] = vf;
                Zv4[gidx] = vv;
            }
        }
        __syncthreads();  // protect LDS before next tile's staging overwrites
    }

    // --- log-likelihood reduction: wave shuffle -> LDS -> one atomic/block ---
    float ll = valid ? ll2 * 0.69314718055994531f : 0.0f;
    #pragma unroll
    for (int off = 32; off > 0; off >>= 1) {
        ll += __shfl_down(ll, off, 64);
    }
    const int wid  = tid >> 6;
    const int lane = tid & 63;
    if (lane == 0) wave_ll[wid] = ll;
    __syncthreads();
    if (tid == 0) {
        float sacc = 0.0f;
        #pragma unroll
        for (int w = 0; w < NB / 64; ++w) sacc += wave_ll[w];
        atomicAdd(ll_out, sacc);
    }
}

extern "C" void kernel_launch(void* const* d_in, const int* in_sizes, int n_in,
                              void* d_out, int out_size, void* d_ws, size_t ws_size,
                              hipStream_t stream) {
    const int N = in_sizes[0];  // G is (N,1)

    const float* G   = (const float*)d_in[0];
    const float* S   = (const float*)d_in[1];
    const float* C   = (const float*)d_in[2];
    const float* Y   = (const float*)d_in[3];
    const float* L   = (const float*)d_in[4];
    const float* psi = (const float*)d_in[5];
    const float* gS  = (const float*)d_in[6];
    const float* gC  = (const float*)d_in[7];
    const float* gG  = (const float*)d_in[8];
    const float* gGS = (const float*)d_in[9];
    const float* gGC = (const float*)d_in[10];
    const float* gLw = (const float*)d_in[11];
    const float* lsZ = (const float*)d_in[12];
    const float* b0  = (const float*)d_in[13];
    const float* bZ  = (const float*)d_in[14];
    const float* bS  = (const float*)d_in[15];
    const float* bG  = (const float*)d_in[16];
    const float* bGS = (const float*)d_in[17];
    const float* bLw = (const float*)d_in[18];

    float* out = (float*)d_out;
    float* Zf = out;
    float* Zv = out + (size_t)N * TT;
    float* ll = out + (size_t)2 * N * TT;

    zero_ll_kernel<<<1, 1, 0, stream>>>(ll);

    const int blocks = (N + NB - 1) / NB;
    hmm_filter_kernel<<<blocks, NB, 0, stream>>>(
        G, S, C, Y, L, psi, gS, gC, gG, gGS, gGC, gLw, lsZ,
        b0, bZ, bS, bG, bGS, bLw, Zf, Zv, ll, N);
}

// Round 3
// 505.258 us; speedup vs baseline: 1.2420x; 1.0011x over previous
//
#include <hip/hip_runtime.h>

// HiddenMarkovGFormulaV2: N independent sequential filters over T=64 steps.
// Memory-bound streaming problem (~518 MB ideal traffic -> ~82 us floor).
//
// v4 theory: v1/v2/v3 were all pinned at 2.4-2.7 TB/s (HBM 43% idle, VALU
// 88% idle) because (a) hipcc emits s_waitcnt vmcnt(0) before EVERY
// __syncthreads -> prefetched loads get force-drained at each of 3 barriers
// per tile and all blocks phase-lock into burst/drain cycles, and (b) the
// final atomicAdd to ONE global address serializes 1563 device-scope RMWs
// (~125 ns each ~ the entire 194 us wall).
//
// v4 structure: the (N,T) transpose only needs WAVE-scope cooperation.
// Each wave owns 64 rows and a private LDS slice; wave-internal LDS
// producer->consumer needs only lgkmcnt (lockstep lanes), NO barriers ->
// no vmcnt drains in the main loop -> each wave is an independent
// streaming pipeline with next-chunk loads always in flight.
// ll: per-block partial to d_ws + tiny reduce kernel; zero atomics.
//
//  * block = 128 = 2 independent waves; LDS 16.9 KB -> 9 blocks/CU
//    (18 waves/CU), pad 66 -> every LDS access exactly 2-way (free).
//  * All global loads/stores remain 64-B-sector coalesced (wave covers
//    16 rows x 64 B per instruction).
//  * Inner math unchanged from v3 (passed): one v_exp sigmoid, one
//    v_log2 ll term, v_rcp for both divides, Y sign-packed into C.

#define TT 64          // timesteps (fixed by reference)
#define KK 3           // covariates (fixed by reference)
#define BT 128         // threads per block = 2 waves
#define WPB (BT / 64)  // waves per block
#define CT 16          // timesteps per chunk (64 B per row per chunk)
#define LDP 66         // pad: 66 mod 32 == 2 -> 2-way on all patterns (free)

__global__ __launch_bounds__(256) void ll_reduce_kernel(
    const float* __restrict__ part, float* __restrict__ ll_out, int nb)
{
    float s = 0.0f;
    for (int i = threadIdx.x; i < nb; i += 256) s += part[i];
    #pragma unroll
    for (int off = 32; off > 0; off >>= 1) s += __shfl_down(s, off, 64);
    __shared__ float ws[4];
    const int wid = threadIdx.x >> 6, lane = threadIdx.x & 63;
    if (lane == 0) ws[wid] = s;
    __syncthreads();
    if (threadIdx.x == 0) *ll_out = ws[0] + ws[1] + ws[2] + ws[3];
}

__global__ __launch_bounds__(BT, 4) void hmm_filter_kernel(
    const float* __restrict__ G,   // (N,1)
    const float* __restrict__ S,   // (N,T)
    const float* __restrict__ C,   // (N,T)
    const float* __restrict__ Y,   // (N,T)
    const float* __restrict__ L,   // (N,K)
    const float* __restrict__ p_psi,
    const float* __restrict__ p_gS,
    const float* __restrict__ p_gC,
    const float* __restrict__ p_gG,
    const float* __restrict__ p_gGS,
    const float* __restrict__ p_gGC,
    const float* __restrict__ p_gLw,  // (1,K)
    const float* __restrict__ p_lsZ,
    const float* __restrict__ p_b0,
    const float* __restrict__ p_bZ,
    const float* __restrict__ p_bS,
    const float* __restrict__ p_bG,
    const float* __restrict__ p_bGS,
    const float* __restrict__ p_bLw,  // (1,K)
    float* __restrict__ Zf,           // (N,T)
    float* __restrict__ Zv,           // (N,T)
    float* __restrict__ ll_part,      // (num_blocks,) partial sums
    int N)
{
    // Per-wave private LDS slices: no cross-wave sharing in the main loop.
    __shared__ float sS [WPB][CT][LDP];   // in: S         out: Z_filtered
    __shared__ float sCY[WPB][CT][LDP];   // in: C|sign(Y) out: Z_variance
    __shared__ float wll[WPB];

    const int tid   = threadIdx.x;
    const int w     = tid >> 6;          // wave id within block
    const int l     = tid & 63;          // lane id
    const int wbase = blockIdx.x * BT + w * 64;  // first row of this wave
    const int n     = wbase + l;         // row this lane filters
    const bool valid = (n < N);

    // --- uniform parameters (scalar-cached broadcast loads) ---
    const float psi  = p_psi[0];
    const float gS   = p_gS[0];
    const float gC   = p_gC[0];
    const float gG   = p_gG[0];
    const float gGS  = p_gGS[0];
    const float gGC  = p_gGC[0];
    const float b0   = p_b0[0];
    const float bZ   = p_bZ[0];
    const float bS   = p_bS[0];
    const float bG   = p_bG[0];
    const float bGS  = p_bGS[0];
    const float esz  = expf(p_lsZ[0]);
    const float sigma2 = esz * esz;
    const float psi2 = psi * psi;
    const float bZ2  = bZ * bZ;
    const float gw0 = p_gLw[0], gw1 = p_gLw[1], gw2 = p_gLw[2];
    const float bw0 = p_bLw[0], bw1 = p_bLw[1], bw2 = p_bLw[2];

    // --- per-n constants: fold G and L into per-thread coefficients ---
    float a_s = 0.0f, a_c = 0.0f, zbase = 0.0f, b_s = 0.0f, lbase = 0.0f;
    if (valid) {
        const float Gv = G[n];
        const float l0 = L[n * KK + 0];
        const float l1 = L[n * KK + 1];
        const float l2 = L[n * KK + 2];
        const float gL = l0 * gw0 + l1 * gw1 + l2 * gw2;
        const float bL = l0 * bw0 + l1 * bw1 + l2 * bw2;
        a_s   = gS + gGS * Gv;           // coeff of S_t in transition
        a_c   = gC + gGC * Gv;           // coeff of C_t in transition
        zbase = gG * Gv + gL;            // constant transition term
        b_s   = bS + bGS * Gv;           // coeff of S_t in logit
        lbase = b0 + bG * Gv + bL;       // constant logit term
    } else {
        lbase = b0;                      // keep math finite for dead lanes
    }

    float zm  = 0.0f;   // Z_mean
    float zv  = 1.0f;   // Z_var
    float ll2 = 0.0f;   // log-likelihood accumulated in log2 domain

    const float4* S4 = (const float4*)S;
    const float4* C4 = (const float4*)C;
    const float4* Y4 = (const float4*)Y;
    float4* Zf4 = (float4*)Zf;
    float4* Zv4 = (float4*)Zv;

    // Wave-internal cooperative decomposition of a 64-row x 16-t chunk:
    // lane l handles float4-column cc = l&3 of rows (l>>2) + i*16, i=0..3.
    // Each global load/store instruction touches 16 rows x 64 B: clean
    // 64-B sectors, fully consumed.
    const int rq = l >> 2;               // 0..15
    const int cc = l & 3;                // which float4 within the 64-B chunk
    const int tb = cc * 4;               // first timestep of that float4

    float4 rs[4], rc[4], ry[4];          // prefetch registers

    // --- prologue: load chunk 0 ---
    #pragma unroll
    for (int i = 0; i < 4; ++i) {
        const int nn = wbase + rq + i * 16;
        if (nn < N) {
            const int gidx = nn * (TT / 4) + cc;
            rs[i] = S4[gidx]; rc[i] = C4[gidx]; ry[i] = Y4[gidx];
        } else {
            rs[i] = make_float4(0, 0, 0, 0);
            rc[i] = rs[i]; ry[i] = rs[i];
        }
    }

    for (int t0 = 0; t0 < TT; t0 += CT) {
        // --- stage prefetched regs -> LDS (transpose + Y sign-pack) ---
        // pack: bits(1.0f)<<8 == 0x80000000, bits(0.0f) == 0; C >= 0.
        // Wave-private slice: only lgkmcnt ordering needed, no barrier.
        #pragma unroll
        for (int i = 0; i < 4; ++i) {
            const int r = rq + i * 16;
            sS[w][tb + 0][r] = rs[i].x; sS[w][tb + 1][r] = rs[i].y;
            sS[w][tb + 2][r] = rs[i].z; sS[w][tb + 3][r] = rs[i].w;
            sCY[w][tb + 0][r] = __uint_as_float(__float_as_uint(rc[i].x) | (__float_as_uint(ry[i].x) << 8));
            sCY[w][tb + 1][r] = __uint_as_float(__float_as_uint(rc[i].y) | (__float_as_uint(ry[i].y) << 8));
            sCY[w][tb + 2][r] = __uint_as_float(__float_as_uint(rc[i].z) | (__float_as_uint(ry[i].z) << 8));
            sCY[w][tb + 3][r] = __uint_as_float(__float_as_uint(rc[i].w) | (__float_as_uint(ry[i].w) << 8));
        }

        // --- issue next chunk's global loads (stay in flight across the
        //     whole compute+store phase; nothing ever drains vmcnt(0)) ---
        if (t0 + CT < TT) {
            const int fo = ((t0 + CT) >> 2) + cc;
            #pragma unroll
            for (int i = 0; i < 4; ++i) {
                const int nn = wbase + rq + i * 16;
                if (nn < N) {           // invalid rows keep their zeros
                    const int gidx = nn * (TT / 4) + fo;
                    rs[i] = S4[gidx]; rc[i] = C4[gidx]; ry[i] = Y4[gidx];
                }
            }
        }

        // ensure staged LDS writes are visible to all lanes of this wave
        asm volatile("s_waitcnt lgkmcnt(0)" ::: "memory");

        // --- sequential filter over this chunk's CT steps ---
        // Lane l reads/writes only column l: in-place staging race-free.
        #pragma unroll
        for (int t = 0; t < CT; ++t) {
            const float s      = sS[w][t][l];
            const unsigned cyb = __float_as_uint(sCY[w][t][l]);
            const float c      = __uint_as_float(cyb & 0x7fffffffu);
            const bool  yb     = (cyb >> 31) != 0u;

            const float zpred = fmaf(psi, zm, fmaf(a_s, s, fmaf(a_c, c, zbase)));
            const float zpvar = fmaf(psi2, zv, sigma2);

            float logit = fmaf(bZ, zpred, fmaf(b_s, s, lbase));
            logit = fminf(fmaxf(logit, -20.0f), 20.0f);
            // sigmoid: one v_exp_f32 + one v_rcp_f32
            const float p   = __builtin_amdgcn_rcpf(1.0f + __expf(-logit));
            const float omp = 1.0f - p;

            const float ymp = yb ? omp : -p;     // (y - p), y in {0,1}
            const float sel = yb ? p : omp;      // prob of observed outcome

            const float hess = fmaf(bZ2 * p, omp, 1e-6f);
            // 1/(1/zpvar + hess) == zpvar/(1 + zpvar*hess): one v_rcp_f32
            const float zpostvar  = zpvar * __builtin_amdgcn_rcpf(fmaf(zpvar, hess, 1.0f));
            const float zpostmean = fmaf(zpostvar * bZ, ymp, zpred);

            // y*log(p+e) + (1-y)*log(1-p+e) == log(sel+e) for binary y;
            // accumulate log2, scale by ln2 once after the loop.
            ll2 += __log2f(sel + 1e-10f);

            zm = zpostmean;
            zv = zpostvar;
            sS [w][t][l] = zpostmean;   // stage Z_filtered
            sCY[w][t][l] = zpostvar;    // stage Z_variance
        }

        // lanes are lockstep; drain result ds_writes before cross-lane read
        asm volatile("s_waitcnt lgkmcnt(0)" ::: "memory");

        // --- cooperative read-back + coalesced store (wave-internal) ---
        #pragma unroll
        for (int i = 0; i < 4; ++i) {
            const int r  = rq + i * 16;
            const int nn = wbase + r;
            if (nn < N) {
                float4 vf, vv;
                vf.x = sS [w][tb + 0][r]; vf.y = sS [w][tb + 1][r];
                vf.z = sS [w][tb + 2][r]; vf.w = sS [w][tb + 3][r];
                vv.x = sCY[w][tb + 0][r]; vv.y = sCY[w][tb + 1][r];
                vv.z = sCY[w][tb + 2][r]; vv.w = sCY[w][tb + 3][r];
                const int gidx = nn * (TT / 4) + (t0 >> 2) + cc;
                Zf4[gidx] = vf;
                Zv4[gidx] = vv;
            }
        }
        // next iteration's staging may not overwrite this chunk's slots
        // until the read-back ds_reads retire (same wave: lgkmcnt order);
        // the compiler inserts the wait from its own alias analysis.
    }

    // --- ll reduction: wave shuffle -> one partial per block (no atomics) ---
    float ll = valid ? ll2 * 0.69314718055994531f : 0.0f;
    #pragma unroll
    for (int off = 32; off > 0; off >>= 1) {
        ll += __shfl_down(ll, off, 64);
    }
    if (l == 0) wll[w] = ll;
    __syncthreads();   // once per block, after the main loop: harmless
    if (tid == 0) {
        float sacc = 0.0f;
        #pragma unroll
        for (int ww = 0; ww < WPB; ++ww) sacc += wll[ww];
        ll_part[blockIdx.x] = sacc;
    }
}

extern "C" void kernel_launch(void* const* d_in, const int* in_sizes, int n_in,
                              void* d_out, int out_size, void* d_ws, size_t ws_size,
                              hipStream_t stream) {
    const int N = in_sizes[0];  // G is (N,1)

    const float* G   = (const float*)d_in[0];
    const float* S   = (const float*)d_in[1];
    const float* C   = (const float*)d_in[2];
    const float* Y   = (const float*)d_in[3];
    const float* L   = (const float*)d_in[4];
    const float* psi = (const float*)d_in[5];
    const float* gS  = (const float*)d_in[6];
    const float* gC  = (const float*)d_in[7];
    const float* gG  = (const float*)d_in[8];
    const float* gGS = (const float*)d_in[9];
    const float* gGC = (const float*)d_in[10];
    const float* gLw = (const float*)d_in[11];
    const float* lsZ = (const float*)d_in[12];
    const float* b0  = (const float*)d_in[13];
    const float* bZ  = (const float*)d_in[14];
    const float* bS  = (const float*)d_in[15];
    const float* bG  = (const float*)d_in[16];
    const float* bGS = (const float*)d_in[17];
    const float* bLw = (const float*)d_in[18];

    float* out = (float*)d_out;
    float* Zf = out;
    float* Zv = out + (size_t)N * TT;
    float* ll = out + (size_t)2 * N * TT;

    float* ll_part = (float*)d_ws;   // num_blocks floats of workspace

    const int blocks = (N + BT - 1) / BT;
    hmm_filter_kernel<<<blocks, BT, 0, stream>>>(
        G, S, C, Y, L, psi, gS, gC, gG, gGS, gGC, gLw, lsZ,
        b0, bZ, bS, bG, bGS, bLw, Zf, Zv, ll_part, N);
    ll_reduce_kernel<<<1, 256, 0, stream>>>(ll_part, ll, blocks);
}

// Round 4
// 491.076 us; speedup vs baseline: 1.2779x; 1.0289x over previous
//
#include <hip/hip_runtime.h>

// HiddenMarkovGFormulaV2: N independent sequential filters over T=64 steps.
// Memory-bound streaming problem (~518 MB ideal traffic -> ~82 us floor).
//
// v5 theory: v1-v4 (tiled over t in 4 passes) were all pinned at 2.4-2.8
// TB/s = 44% of the 6.3 TB/s streaming rate, with VALU 88% idle and no
// barriers/atomics/conflicts left (v4). The invariant: every version read
// and wrote a 64 B tooth out of each 256 B row per pass, teeth ~1/4 kernel
// apart in time; v2 (32 B teeth) proved L2 retains nothing between passes
// (FETCH doubled). DRAM row-buffers deliver ~256 B per 1 KB activation and
// every row is re-activated 4x -> ~44% of streaming. Classic strided-comb
// derate.
//
// v5 structure: close the comb in time. One thread = one row, FULL row in
// registers: 48 dwordx4 loads issued as one program-order burst (pinned by
// sched_barrier(0); vmcnt FIFO lets compute start when chunk 0 lands),
// 64-step scan entirely in registers, outputs accumulated in registers,
// one 32-store epilogue burst. Reads and writes are dense contiguous
// 16 KB spans per wave, all teeth of every row in flight together.
// No LDS, no transpose, no __syncthreads anywhere.
//  * VGPR ~230 -> 8 waves/CU (launch_bounds(256,2)); MLP = 8x48 KB
//    in flight per CU -- occupancy is irrelevant, latency fully covered.
//  * ll: per-wave shuffle reduce -> per-wave partial in d_ws -> tiny
//    reduce kernel (zero atomics, unchanged from v4).
//  * Step math bit-identical to v3/v4 (passed, absmax 0.0078):
//    one v_exp sigmoid, one v_log2 ll term, v_rcp for both divides.

#define TT 64          // timesteps (fixed by reference)
#define KK 3           // covariates (fixed by reference)
#define BT 256         // threads per block = 4 waves

__global__ __launch_bounds__(256) void ll_reduce_kernel(
    const float* __restrict__ part, float* __restrict__ ll_out, int nw)
{
    float s = 0.0f;
    for (int i = threadIdx.x; i < nw; i += 256) s += part[i];
    #pragma unroll
    for (int off = 32; off > 0; off >>= 1) s += __shfl_down(s, off, 64);
    __shared__ float ws[4];
    const int wid = threadIdx.x >> 6, lane = threadIdx.x & 63;
    if (lane == 0) ws[wid] = s;
    __syncthreads();
    if (threadIdx.x == 0) *ll_out = ws[0] + ws[1] + ws[2] + ws[3];
}

// One filter step. Inputs s,c,y; updates zm, zv, ll2; emits mean/var.
#define STEP(SV, CV, YV, OM, OV)                                            \
    {                                                                       \
        const float s_  = (SV);                                             \
        const float c_  = (CV);                                             \
        const bool  yb_ = ((YV) != 0.0f);                                   \
        const float zpred = fmaf(psi, zm, fmaf(a_s, s_, fmaf(a_c, c_, zbase))); \
        const float zpvar = fmaf(psi2, zv, sigma2);                         \
        float logit = fmaf(bZ, zpred, fmaf(b_s, s_, lbase));                \
        logit = fminf(fmaxf(logit, -20.0f), 20.0f);                         \
        const float p_   = __builtin_amdgcn_rcpf(1.0f + __expf(-logit));    \
        const float omp_ = 1.0f - p_;                                       \
        const float ymp_ = yb_ ? omp_ : -p_;                                \
        const float sel_ = yb_ ? p_ : omp_;                                 \
        const float hess_ = fmaf(bZ2 * p_, omp_, 1e-6f);                    \
        const float zpostvar_  = zpvar * __builtin_amdgcn_rcpf(fmaf(zpvar, hess_, 1.0f)); \
        const float zpostmean_ = fmaf(zpostvar_ * bZ, ymp_, zpred);         \
        ll2 += __log2f(sel_ + 1e-10f);                                      \
        zm = zpostmean_;                                                    \
        zv = zpostvar_;                                                     \
        (OM) = zpostmean_;                                                  \
        (OV) = zpostvar_;                                                   \
    }

__global__ __launch_bounds__(BT, 2) void hmm_filter_kernel(
    const float* __restrict__ G,   // (N,1)
    const float* __restrict__ S,   // (N,T)
    const float* __restrict__ C,   // (N,T)
    const float* __restrict__ Y,   // (N,T)
    const float* __restrict__ L,   // (N,K)
    const float* __restrict__ p_psi,
    const float* __restrict__ p_gS,
    const float* __restrict__ p_gC,
    const float* __restrict__ p_gG,
    const float* __restrict__ p_gGS,
    const float* __restrict__ p_gGC,
    const float* __restrict__ p_gLw,  // (1,K)
    const float* __restrict__ p_lsZ,
    const float* __restrict__ p_b0,
    const float* __restrict__ p_bZ,
    const float* __restrict__ p_bS,
    const float* __restrict__ p_bG,
    const float* __restrict__ p_bGS,
    const float* __restrict__ p_bLw,  // (1,K)
    float* __restrict__ Zf,           // (N,T)
    float* __restrict__ Zv,           // (N,T)
    float* __restrict__ ll_part,      // one partial per wave
    int N)
{
    const int tid = threadIdx.x;
    const int n   = blockIdx.x * BT + tid;
    const bool valid = (n < N);

    // --- uniform parameters (scalar-cached broadcast loads) ---
    const float psi  = p_psi[0];
    const float gS   = p_gS[0];
    const float gC   = p_gC[0];
    const float gG   = p_gG[0];
    const float gGS  = p_gGS[0];
    const float gGC  = p_gGC[0];
    const float b0   = p_b0[0];
    const float bZ   = p_bZ[0];
    const float bS   = p_bS[0];
    const float bG   = p_bG[0];
    const float bGS  = p_bGS[0];
    const float esz  = expf(p_lsZ[0]);
    const float sigma2 = esz * esz;
    const float psi2 = psi * psi;
    const float bZ2  = bZ * bZ;
    const float gw0 = p_gLw[0], gw1 = p_gLw[1], gw2 = p_gLw[2];
    const float bw0 = p_bLw[0], bw1 = p_bLw[1], bw2 = p_bLw[2];

    // --- per-n constants: fold G and L into per-thread coefficients ---
    float a_s = 0.0f, a_c = 0.0f, zbase = 0.0f, b_s = 0.0f, lbase = 0.0f;
    if (valid) {
        const float Gv = G[n];
        const float l0 = L[n * KK + 0];
        const float l1 = L[n * KK + 1];
        const float l2 = L[n * KK + 2];
        const float gL = l0 * gw0 + l1 * gw1 + l2 * gw2;
        const float bL = l0 * bw0 + l1 * bw1 + l2 * bw2;
        a_s   = gS + gGS * Gv;           // coeff of S_t in transition
        a_c   = gC + gGC * Gv;           // coeff of C_t in transition
        zbase = gG * Gv + gL;            // constant transition term
        b_s   = bS + bGS * Gv;           // coeff of S_t in logit
        lbase = b0 + bG * Gv + bL;       // constant logit term
    } else {
        lbase = b0;                      // keep math finite for dead lanes
    }

    const float4* S4 = (const float4*)S;
    const float4* C4 = (const float4*)C;
    const float4* Y4 = (const float4*)Y;
    float4* Zf4 = (float4*)Zf;
    float4* Zv4 = (float4*)Zv;
    const int rb = n * (TT / 4);         // float4 index of this row's start

    // --- load burst: the ENTIRE row of S, C, Y (48 dwordx4 in flight) ---
    // Interleaved by chunk so consumption order == FIFO completion order:
    // chunk c's compute waits vmcnt(~45-3c), everything later stays in
    // flight. sched_barrier(0) pins the whole burst above the scan.
    float4 rs[TT / 4], rc[TT / 4], ry[TT / 4];
    if (valid) {
        #pragma unroll
        for (int i = 0; i < TT / 4; ++i) {
            rs[i] = S4[rb + i];
            rc[i] = C4[rb + i];
            ry[i] = Y4[rb + i];
        }
    } else {
        #pragma unroll
        for (int i = 0; i < TT / 4; ++i) {
            rs[i] = make_float4(0, 0, 0, 0);
            rc[i] = rs[i]; ry[i] = rs[i];
        }
    }
    __builtin_amdgcn_sched_barrier(0);

    // --- 64-step scan fully in registers; outputs accumulate in regs ---
    float4 of[TT / 4], ov[TT / 4];
    float zm  = 0.0f;   // Z_mean
    float zv  = 1.0f;   // Z_var
    float ll2 = 0.0f;   // log-likelihood accumulated in log2 domain

    #pragma unroll
    for (int i = 0; i < TT / 4; ++i) {
        STEP(rs[i].x, rc[i].x, ry[i].x, of[i].x, ov[i].x);
        STEP(rs[i].y, rc[i].y, ry[i].y, of[i].y, ov[i].y);
        STEP(rs[i].z, rc[i].z, ry[i].z, of[i].z, ov[i].z);
        STEP(rs[i].w, rc[i].w, ry[i].w, of[i].w, ov[i].w);
    }

    // --- store burst: full rows of Zf then Zv (32 dwordx4) ---
    if (valid) {
        #pragma unroll
        for (int i = 0; i < TT / 4; ++i) Zf4[rb + i] = of[i];
        #pragma unroll
        for (int i = 0; i < TT / 4; ++i) Zv4[rb + i] = ov[i];
    }

    // --- ll reduction: wave shuffle -> one partial per wave (no atomics,
    //     no LDS, no syncthreads) ---
    float ll = valid ? ll2 * 0.69314718055994531f : 0.0f;
    #pragma unroll
    for (int off = 32; off > 0; off >>= 1) {
        ll += __shfl_down(ll, off, 64);
    }
    if ((tid & 63) == 0) {
        ll_part[blockIdx.x * (BT / 64) + (tid >> 6)] = ll;
    }
}

extern "C" void kernel_launch(void* const* d_in, const int* in_sizes, int n_in,
                              void* d_out, int out_size, void* d_ws, size_t ws_size,
                              hipStream_t stream) {
    const int N = in_sizes[0];  // G is (N,1)

    const float* G   = (const float*)d_in[0];
    const float* S   = (const float*)d_in[1];
    const float* C   = (const float*)d_in[2];
    const float* Y   = (const float*)d_in[3];
    const float* L   = (const float*)d_in[4];
    const float* psi = (const float*)d_in[5];
    const float* gS  = (const float*)d_in[6];
    const float* gC  = (const float*)d_in[7];
    const float* gG  = (const float*)d_in[8];
    const float* gGS = (const float*)d_in[9];
    const float* gGC = (const float*)d_in[10];
    const float* gLw = (const float*)d_in[11];
    const float* lsZ = (const float*)d_in[12];
    const float* b0  = (const float*)d_in[13];
    const float* bZ  = (const float*)d_in[14];
    const float* bS  = (const float*)d_in[15];
    const float* bG  = (const float*)d_in[16];
    const float* bGS = (const float*)d_in[17];
    const float* bLw = (const float*)d_in[18];

    float* out = (float*)d_out;
    float* Zf = out;
    float* Zv = out + (size_t)N * TT;
    float* ll = out + (size_t)2 * N * TT;

    float* ll_part = (float*)d_ws;   // one float per wave of workspace

    const int blocks = (N + BT - 1) / BT;
    const int nwaves = blocks * (BT / 64);
    hmm_filter_kernel<<<blocks, BT, 0, stream>>>(
        G, S, C, Y, L, psi, gS, gC, gG, gGS, gGC, gLw, lsZ,
        b0, bZ, bS, bG, bGS, bLw, Zf, Zv, ll_part, N);
    ll_reduce_kernel<<<1, 256, 0, stream>>>(ll_part, ll, nwaves);
}